// Round 7
// baseline (194.693 us; speedup 1.0000x reference)
//
#include <hip/hip_runtime.h>

// Problem constants (fixed by setup_inputs / reference)
#define BN  4       // batch
#define NPT 16384   // points per batch
#define NCC 1024    // FPS centroids (cap on unique orbit length)
#define KNN 32      // neighbors

// KNN select parameters
#define HBINS    2048   // 11-bit level-1 histogram
#define CCH      4      // centroids per chunk-block
#define CAND_CAP 768    // boundary-bin candidate cap (overflow -> exact drill)

// Workspace layout (bytes). Total ~305 KB.
#define OFF_CCOUNT 0                          // BN ints
#define OFF_SCOUNT 64                         // BN ints
#define OFF_SBITS  128                        // BN*(NPT/32) u32 = 8 KB
#define OFF_POOL   (128 + BN*(NPT/32)*4)      // BN*NCC floats = 16 KB
#define OFF_CLIST  (OFF_POOL + BN*NCC*4)      // BN*NCC ints = 16 KB
#define OFF_H1     (OFF_CLIST + BN*NCC*4)     // BN*512 floats = 8 KB
#define OFF_SLIST  (OFF_H1 + BN*512*4)        // BN*NPT ints = 256 KB

typedef short bf16x8 __attribute__((ext_vector_type(8)));
typedef float f32x4  __attribute__((ext_vector_type(4)));
typedef float f32x2  __attribute__((ext_vector_type(2)));

__device__ __forceinline__ short f2bf(float f) {   // RNE fp32 -> bf16
    unsigned u = __float_as_uint(f);
    return (short)((u + 0x7fffu + ((u >> 16) & 1u)) >> 16);
}
__device__ __forceinline__ bf16x8 cvt8(const float* __restrict__ p) {
    bf16x8 v;
#pragma unroll
    for (int j = 0; j < 8; ++j) v[j] = f2bf(p[j]);
    return v;
}

// ---------------------------------------------------------------------------
// FPS v5: structure = proven v4 (1 barrier/iter, 3-slot rotating packed-u64
// argmax, deferred seen-marking, s_load coords). New: (a) distance loop on
// float2 pairs under fp contract(off) -- same per-element IEEE ops, same
// (dx^2+dy^2)+dz^2 grouping, same ascending-index tie order => bit-identical
// to the __f*_rn scalar version, but eligible for v_pk_{add,mul}_f32 packed
// issue (2 pts/instr). (b) zeroes this batch's workspace slices (ccount,
// scount, sbits, pool) -> the separate fill node is gone.
// ---------------------------------------------------------------------------
__global__ __launch_bounds__(512) void fps_kernel(const float* __restrict__ x,
    const int* __restrict__ far_init, int* __restrict__ clist, int* __restrict__ ccount,
    int* __restrict__ scount, unsigned* __restrict__ sbits, float* __restrict__ pool)
{
#pragma clang fp contract(off)
    const int b = blockIdx.x, t = threadIdx.x;
    __shared__ __align__(16) unsigned char seen[NPT];
    __shared__ unsigned long long slot[3];

    // ---- workspace zeroing for this batch (replaces hipMemsetAsync) ----
    sbits[b*(NPT/32) + t] = 0u;                   // 512 u32
    pool[b*NCC + t] = 0.0f;                       // 1024 floats
    pool[b*NCC + 512 + t] = 0.0f;
    if (t == 0) { ccount[b] = 0; scount[b] = 0; }

    const float* xb = x + (size_t)b * NPT * 3;
    // pairs (ia, ia+512), ia = t + (q<<10): ascending index order preserved
    f32x2 px[16], py[16], pz[16];
#pragma unroll
    for (int q = 0; q < 16; ++q) {
        int ia = t + (q << 10), ib = ia + 512;
        px[q] = f32x2{xb[ia*3+0], xb[ib*3+0]};
        py[q] = f32x2{xb[ia*3+1], xb[ib*3+1]};
        pz[q] = f32x2{xb[ia*3+2], xb[ib*3+2]};
    }
    ((uint4*)seen)[t]       = make_uint4(0,0,0,0);
    ((uint4*)seen)[t + 512] = make_uint4(0,0,0,0);
    if (t == 0) { slot[0] = 0ull; slot[1] = 0ull; slot[2] = 0ull; }
    int prev_bx = far_init[b];                    // uniform (same global read)
    __syncthreads();
    int pbs = __builtin_amdgcn_readfirstlane(prev_bx);
    float cx = xb[pbs*3], cy = xb[pbs*3+1], cz = xb[pbs*3+2];

    int done = 0;
    for (int it = 0; it < NCC-1; ++it) {
        const int p = it % 3;
        const f32x2 cX = {cx, cx}, cY = {cy, cy}, cZ = {cz, cz};
        float best = -1.0f; int bi = 0;
#pragma unroll
        for (int q = 0; q < 16; ++q) {
            f32x2 dx = px[q] - cX;
            f32x2 dy = py[q] - cY;
            f32x2 dz = pz[q] - cZ;
            f32x2 m1 = dx * dx;
            f32x2 m2 = dy * dy;
            f32x2 m3 = dz * dz;
            f32x2 s  = (m1 + m2) + m3;            // exact grouping of reference
            int ia = t + (q << 10);
            if (s.x > best) { best = s.x; bi = ia; }        // strict >: first max
            if (s.y > best) { best = s.y; bi = ia + 512; }
        }
#pragma unroll
        for (int m = 1; m < 64; m <<= 1) {
            float od = __shfl_xor(best, m, 64);
            int   oi = __shfl_xor(bi,   m, 64);
            if (od > best || (od == best && oi < bi)) { best = od; bi = oi; }
        }
        if ((t & 63) == 0) {
            unsigned long long pk =
                (((unsigned long long)__float_as_uint(best)) << 32)
                | (unsigned)(NPT - 1 - bi);
            atomicMax(&slot[p], pk);
        }
        if (t == 0) seen[prev_bx] = 1;            // pre-barrier write, no readers now
        __syncthreads();                          // THE barrier
        int bx = NPT - 1 - (int)(unsigned)(slot[p] & 0xFFFFFFFFull);
        if (t == 0) slot[(it + 2) % 3] = 0ull;    // safe: barrier-separated both ways
        if (seen[bx]) { done = 1; break; }        // uniform (stable post-barrier)
        prev_bx = bx;
        int bxs = __builtin_amdgcn_readfirstlane(bx);
        cx = xb[bxs*3]; cy = xb[bxs*3+1]; cz = xb[bxs*3+2];
    }
    if (!done && t == 0) seen[prev_bx] = 1;       // full-length orbit: mark last
    __syncthreads();
    // Emit unique-centroid list (order-free; downstream is set-invariant).
#pragma unroll
    for (int j = 0; j < 32; ++j) {
        int idx = t + (j << 9);
        if (seen[idx]) {
            int pos = atomicAdd(&ccount[b], 1);
            clist[b * NCC + pos] = idx;
        }
    }
}

// ---------------------------------------------------------------------------
// KNN v4: chunk-PARALLEL (proven), now BRANCHLESS inner loops: the chunk's
// centroid slots are tail-clamped (duplicate of the last centroid). A dup
// centroid computes a dup tau -> union-mark unchanged (set semantics).
// ---------------------------------------------------------------------------
__device__ __forceinline__ unsigned key_of(float px, float py, float pz, float xn,
                                           float cx, float cy, float cz, float cn)
{
    float dot = __fadd_rn(__fadd_rn(__fmul_rn(cx,px), __fmul_rn(cy,py)), __fmul_rn(cz,pz));
    float d2  = __fsub_rn(__fadd_rn(cn, xn), __fmul_rn(2.0f, dot));
    unsigned u = __float_as_uint(d2);
    return u ^ ((u >> 31) ? 0xFFFFFFFFu : 0x80000000u);
}

__device__ __forceinline__ void wave_scan_bins(const unsigned* __restrict__ H,
    int nbins, int rem, int lane, int* __restrict__ out_bin, int* __restrict__ out_below)
{
    int per = nbins >> 6;
    int base = lane * per;
    unsigned part = 0;
    for (int q = 0; q < per; ++q) part += H[base + q];
    unsigned inc = part;
#pragma unroll
    for (int m = 1; m < 64; m <<= 1) {
        unsigned u = __shfl_up(inc, m, 64);
        if (lane >= m) inc += u;
    }
    unsigned exc = inc - part;
    unsigned long long mk = __ballot(exc < (unsigned)rem && inc >= (unsigned)rem);
    int src = __ffsll((long long)mk) - 1;
    if (lane == src) {
        unsigned run = exc; int bb = base;
        for (int q = 0; q < per; ++q) {
            unsigned h = H[base + q];
            if (run + h >= (unsigned)rem) { bb = base + q; break; }
            run += h;
        }
        *out_bin = bb; *out_below = (int)run;
    }
}

__global__ __launch_bounds__(1024) void knn_kernel(const float* __restrict__ x,
    const int* __restrict__ clist, const int* __restrict__ ccount,
    unsigned* __restrict__ sbits, int* __restrict__ slist, int* __restrict__ scount)
{
    const int b = blockIdx.y, t = threadIdx.x;
    const int lane = t & 63, w = t >> 6;
    const int cnt = ccount[b];
    const int cbase = blockIdx.x * CCH;
    if (cbase >= cnt) return;                  // uniform exit, before any barrier
    const float* xb = x + (size_t)b * NPT * 3;

    __shared__ unsigned hist[CCH * HBINS];     // 32 KB
    __shared__ unsigned cand[CCH * CAND_CAP];  // 12 KB
    __shared__ float cpx[CCH], cpy[CCH], cpz[CCH], cpn[CCH];
    __shared__ unsigned candCnt[CCH];
    __shared__ int s_bb[CCH], s_below[CCH], s_rrem[CCH], s_need[CCH], s_pref[CCH];
    __shared__ unsigned s_tau[CCH];
    __shared__ int s_tbin, s_tbelow;

    if (t < CCH) {
        int ci = clist[b * NCC + min(cbase + t, cnt - 1)];   // tail-clamp dup
        float cx = xb[ci*3], cy = xb[ci*3+1], cz = xb[ci*3+2];
        cpx[t] = cx; cpy[t] = cy; cpz[t] = cz;
        cpn[t] = __fadd_rn(__fadd_rn(__fmul_rn(cx,cx), __fmul_rn(cy,cy)), __fmul_rn(cz,cz));
        candCnt[t] = 0;
    }
    for (int i = t; i < CCH * HBINS; i += 1024) hist[i] = 0;
    __syncthreads();

    // Sweep 1: level-1 histograms (top 11 bits), all CCH centroids, branchless.
    for (int j = 0; j < NPT/1024; ++j) {
        int i = t + (j << 10);
        float px = xb[i*3], py = xb[i*3+1], pz = xb[i*3+2];
        float xn = __fadd_rn(__fadd_rn(__fmul_rn(px,px), __fmul_rn(py,py)), __fmul_rn(pz,pz));
#pragma unroll
        for (int c = 0; c < CCH; ++c) {
            unsigned key = key_of(px,py,pz,xn, cpx[c],cpy[c],cpz[c],cpn[c]);
            atomicAdd(&hist[c*HBINS + (key >> 21)], 1u);
        }
    }
    __syncthreads();

    if (w < CCH)
        wave_scan_bins(&hist[w*HBINS], HBINS, KNN, lane, &s_bb[w], &s_below[w]);
    __syncthreads();
    if (t < CCH) s_rrem[t] = KNN - s_below[t];
    __syncthreads();

    // Sweep 2: collect candidate keys in each centroid's boundary bin.
    for (int j = 0; j < NPT/1024; ++j) {
        int i = t + (j << 10);
        float px = xb[i*3], py = xb[i*3+1], pz = xb[i*3+2];
        float xn = __fadd_rn(__fadd_rn(__fmul_rn(px,px), __fmul_rn(py,py)), __fmul_rn(pz,pz));
#pragma unroll
        for (int c = 0; c < CCH; ++c) {
            unsigned key = key_of(px,py,pz,xn, cpx[c],cpy[c],cpz[c],cpn[c]);
            if ((int)(key >> 21) == s_bb[c]) {
                unsigned pos = atomicAdd(&candCnt[c], 1u);
                if (pos < CAND_CAP) cand[c*CAND_CAP + pos] = key;
            }
        }
    }
    __syncthreads();

    // Exact tau: rank-select (rrem-th smallest with multiplicity) per wave.
    if (w < CCH) {
        unsigned cc = candCnt[w];
        if (cc <= CAND_CAP) {
            int r = s_rrem[w] - 1;
            const unsigned* C = &cand[w*CAND_CAP];
            for (int idx = lane; idx < (int)cc; idx += 64) {
                unsigned k = C[idx]; int rank = 0;
                for (int q = 0; q < (int)cc; ++q) {
                    unsigned kq = C[q];
                    rank += (kq < k || (kq == k && q < idx)) ? 1 : 0;
                }
                if (rank == r) s_tau[w] = k;
            }
            if (lane == 0) s_need[w] = 0;
        } else if (lane == 0) s_need[w] = 1;
    }
    __syncthreads();

    // Rare exact drill-down for overflowed boundary bins (guaranteed exact).
    for (int c = 0; c < CCH; ++c) {
        if (s_need[c]) {
            const float cx = cpx[c], cy = cpy[c], cz = cpz[c], cn = cpn[c];
            for (int i = t; i < HBINS; i += 1024) hist[i] = 0;
            __syncthreads();
            for (int j = 0; j < NPT/1024; ++j) {
                int i = t + (j << 10);
                float px = xb[i*3], py = xb[i*3+1], pz = xb[i*3+2];
                float xn = __fadd_rn(__fadd_rn(__fmul_rn(px,px), __fmul_rn(py,py)), __fmul_rn(pz,pz));
                unsigned key = key_of(px,py,pz,xn, cx,cy,cz,cn);
                if ((int)(key >> 21) == s_bb[c]) atomicAdd(&hist[(key >> 10) & 2047u], 1u);
            }
            __syncthreads();
            if (w == 0) wave_scan_bins(hist, HBINS, s_rrem[c], lane, &s_tbin, &s_tbelow);
            __syncthreads();
            if (t == 0) { s_pref[c] = (s_bb[c] << 11) | s_tbin; s_rrem[c] -= s_tbelow; }
            __syncthreads();
            for (int i = t; i < 1024; i += 1024) hist[i] = 0;
            __syncthreads();
            for (int j = 0; j < NPT/1024; ++j) {
                int i = t + (j << 10);
                float px = xb[i*3], py = xb[i*3+1], pz = xb[i*3+2];
                float xn = __fadd_rn(__fadd_rn(__fmul_rn(px,px), __fmul_rn(py,py)), __fmul_rn(pz,pz));
                unsigned key = key_of(px,py,pz,xn, cx,cy,cz,cn);
                if ((int)(key >> 10) == s_pref[c]) atomicAdd(&hist[key & 1023u], 1u);
            }
            __syncthreads();
            if (w == 0) wave_scan_bins(hist, 1024, s_rrem[c], lane, &s_tbin, &s_tbelow);
            __syncthreads();
            if (t == 0) s_tau[c] = (((unsigned)s_pref[c]) << 10) | (unsigned)s_tbin;
            __syncthreads();
        }
    }
    __syncthreads();

    // Sweep 3: union-mark (key <= tau) + build compacted list (deduped).
    for (int j = 0; j < NPT/1024; ++j) {
        int i = t + (j << 10);
        float px = xb[i*3], py = xb[i*3+1], pz = xb[i*3+2];
        float xn = __fadd_rn(__fadd_rn(__fmul_rn(px,px), __fmul_rn(py,py)), __fmul_rn(pz,pz));
        bool sel = false;
#pragma unroll
        for (int c = 0; c < CCH; ++c) {
            unsigned key = key_of(px,py,pz,xn, cpx[c],cpy[c],cpz[c],cpn[c]);
            sel |= (key <= s_tau[c]);
        }
        if (sel) {
            unsigned bit = 1u << (i & 31);
            unsigned old = atomicOr(&sbits[b*(NPT/32) + (i >> 5)], bit);
            if (!(old & bit)) {
                int pos = atomicAdd(&scount[b], 1);
                slist[b * NPT + pos] = i;
            }
        }
    }
}

// ---------------------------------------------------------------------------
// MLP v4 (proven R6): MFMA 16x16x32 bf16, weights persistent in VGPR B-frags.
// ---------------------------------------------------------------------------
#define MFMA16(a, bfr, c) __builtin_amdgcn_mfma_f32_16x16x32_bf16(a, bfr, c, 0, 0, 0)

__global__ __launch_bounds__(1024) void mlp_kernel(const float* __restrict__ x,
    const int* __restrict__ sel_list, const int* __restrict__ sel_count,
    const float* __restrict__ w1, const float* __restrict__ b1,
    const float* __restrict__ w2, const float* __restrict__ b2,
    const float* __restrict__ w3, const float* __restrict__ b3,
    const float* __restrict__ w4, const float* __restrict__ b4,
    const float* __restrict__ w5, const float* __restrict__ b5,
    float* __restrict__ pool)
{
    const int b = blockIdx.y, z = blockIdx.z, t = threadIdx.x;
    const int cnt = sel_count[b];
    if ((blockIdx.x << 6) >= cnt) return;      // uniform, before any barrier
    const int lane = t & 63;
    const int w    = __builtin_amdgcn_readfirstlane(t >> 6);  // 0..15
    const int m    = lane & 15, quad = lane >> 4;

    __shared__ __align__(16) short A1[64 * 72];    // 9 KB
    __shared__ __align__(16) short A2[64 * 72];    // 9 KB
    __shared__ __align__(16) short A3[64 * 136];   // 17 KB
    __shared__ float sx[3 * 64];

    // ---- persistent weight fragments (once per block) ----
    const int ocA = (w >> 2) * 16 + m;             // L2/L3 oc (wave>>2 = oc_tile)
    bf16x8 bw2[2], bw3[2], bw4[2][2], bw5[4];
#pragma unroll
    for (int ks = 0; ks < 2; ++ks) {
        bw2[ks] = cvt8(w2 + ocA*64 + ks*32 + quad*8);
        bw3[ks] = cvt8(w3 + ocA*64 + ks*32 + quad*8);
    }
    int oc4i[2];
#pragma unroll
    for (int r2 = 0; r2 < 2; ++r2) {
        oc4i[r2] = ((w >> 2) + 4*r2) * 16 + m;
#pragma unroll
        for (int ks = 0; ks < 2; ++ks)
            bw4[r2][ks] = cvt8(w4 + oc4i[r2]*64 + ks*32 + quad*8);
    }
    const int oc5 = z*256 + w*16 + m;
#pragma unroll
    for (int ks = 0; ks < 4; ++ks)
        bw5[ks] = cvt8(w5 + oc5*128 + ks*32 + quad*8);
    const float bias2 = b2[ocA], bias3 = b3[ocA];
    const float bias4_0 = b4[oc4i[0]], bias4_1 = b4[oc4i[1]];
    const float bias5 = b5[oc5];
    float w1v[4][3], b1v[4];
#pragma unroll
    for (int i = 0; i < 4; ++i) {
        int oc = w*4 + i;
        w1v[i][0] = w1[oc*3+0]; w1v[i][1] = w1[oc*3+1]; w1v[i][2] = w1[oc*3+2];
        b1v[i] = b1[oc];
    }
    const int pt0 = (w & 3) * 16;                  // pt tile for L2/L3/L4

    for (int base = blockIdx.x << 6; base < cnt; base += (32 << 6)) {
        const int npts = min(64, cnt - base);
        __syncthreads();                            // prev tile fully consumed
        if (t < 64) {
            int idx = sel_list[b * NPT + base + min(t, npts - 1)];  // pad = dup last
            const float* xp = x + ((size_t)b * NPT + idx) * 3;
            sx[t] = xp[0]; sx[64 + t] = xp[1]; sx[128 + t] = xp[2];
        }
        __syncthreads();
        {   // L1: 3->64, fp32 VALU, write bf16 [pt][72]
            float x0 = sx[lane], x1 = sx[64 + lane], x2 = sx[128 + lane];
#pragma unroll
            for (int i = 0; i < 4; ++i) {
                float acc = fmaf(x2, w1v[i][2], fmaf(x1, w1v[i][1],
                             fmaf(x0, w1v[i][0], b1v[i])));
                A1[lane*72 + w*4 + i] = f2bf(fmaxf(acc, 0.0f));
            }
        }
        __syncthreads();
        {   // L2: A1 -> A2 (64->64)
            bf16x8 a0 = *(const bf16x8*)&A1[(pt0 + m)*72 + quad*8];
            bf16x8 a1 = *(const bf16x8*)&A1[(pt0 + m)*72 + 32 + quad*8];
            f32x4 d = {0.f, 0.f, 0.f, 0.f};
            d = MFMA16(a0, bw2[0], d);
            d = MFMA16(a1, bw2[1], d);
#pragma unroll
            for (int r = 0; r < 4; ++r)
                A2[(pt0 + quad*4 + r)*72 + ocA] = f2bf(fmaxf(d[r] + bias2, 0.0f));
        }
        __syncthreads();
        {   // L3: A2 -> A1 (64->64)
            bf16x8 a0 = *(const bf16x8*)&A2[(pt0 + m)*72 + quad*8];
            bf16x8 a1 = *(const bf16x8*)&A2[(pt0 + m)*72 + 32 + quad*8];
            f32x4 d = {0.f, 0.f, 0.f, 0.f};
            d = MFMA16(a0, bw3[0], d);
            d = MFMA16(a1, bw3[1], d);
#pragma unroll
            for (int r = 0; r < 4; ++r)
                A1[(pt0 + quad*4 + r)*72 + ocA] = f2bf(fmaxf(d[r] + bias3, 0.0f));
        }
        __syncthreads();
        {   // L4: A1 -> A3 (64->128), 2 oc-tiles per wave
            bf16x8 a0 = *(const bf16x8*)&A1[(pt0 + m)*72 + quad*8];
            bf16x8 a1 = *(const bf16x8*)&A1[(pt0 + m)*72 + 32 + quad*8];
#pragma unroll
            for (int r2 = 0; r2 < 2; ++r2) {
                f32x4 d = {0.f, 0.f, 0.f, 0.f};
                d = MFMA16(a0, bw4[r2][0], d);
                d = MFMA16(a1, bw4[r2][1], d);
                float bs = r2 ? bias4_1 : bias4_0;
#pragma unroll
                for (int r = 0; r < 4; ++r)
                    A3[(pt0 + quad*4 + r)*136 + oc4i[r2]] = f2bf(fmaxf(d[r] + bs, 0.0f));
            }
        }
        __syncthreads();
        {   // L5 (128 -> this block's 256-oc slice) + max-pool
            float vm = 0.0f;                        // relu outputs >= 0
#pragma unroll
            for (int pt4 = 0; pt4 < 4; ++pt4) {
                const int q0 = pt4 * 16;
                f32x4 d = {0.f, 0.f, 0.f, 0.f};
#pragma unroll
                for (int ks = 0; ks < 4; ++ks) {
                    bf16x8 a = *(const bf16x8*)&A3[(q0 + m)*136 + ks*32 + quad*8];
                    d = MFMA16(a, bw5[ks], d);
                }
#pragma unroll
                for (int r = 0; r < 4; ++r)
                    vm = fmaxf(vm, fmaxf(d[r] + bias5, 0.0f));
            }
            vm = fmaxf(vm, __shfl_xor(vm, 16, 64));
            vm = fmaxf(vm, __shfl_xor(vm, 32, 64));
            if (lane < 16)
                atomicMax((int*)&pool[b*NCC + z*256 + w*16 + lane], __float_as_int(vm));
        }
    }
}

// ---------------------------------------------------------------------------
// FC head (proven, fp32 exact). head1: FC1 (1024->512 relu), 4 blocks/batch.
// ---------------------------------------------------------------------------
__global__ __launch_bounds__(1024) void head1_kernel(const float* __restrict__ pool,
    const float* __restrict__ fw1, const float* __restrict__ fb1,
    float* __restrict__ h1g)
{
    const int bo = blockIdx.x, b = blockIdx.y, t = threadIdx.x;
    const int lane = t & 63, w = t >> 6;
    __shared__ float g[1024];
    g[t] = pool[b*NCC + t];
    __syncthreads();
    int o = bo * 128 + w * 8;
#pragma unroll
    for (int i = 0; i < 8; ++i, ++o) {
        float acc = 0.0f;
#pragma unroll
        for (int j = 0; j < 16; ++j) {
            int k = lane + (j << 6);
            acc += g[k] * fw1[o*1024 + k];
        }
#pragma unroll
        for (int m = 1; m < 64; m <<= 1) acc += __shfl_xor(acc, m, 64);
        if (lane == 0) h1g[b*512 + o] = fmaxf(acc + fb1[o], 0.0f);
    }
}

// head2: FC2 (512->256 relu) + FC3 (256->3). One block per batch.
__global__ __launch_bounds__(1024) void head2_kernel(const float* __restrict__ h1g,
    const float* __restrict__ fw2, const float* __restrict__ fb2,
    const float* __restrict__ fw3, const float* __restrict__ fb3,
    float* __restrict__ out)
{
    const int b = blockIdx.x, t = threadIdx.x;
    const int lane = t & 63, w = t >> 6;
    __shared__ float h1[512], h2[256];
    if (t < 512) h1[t] = h1g[b*512 + t];
    __syncthreads();
#pragma unroll
    for (int i = 0; i < 16; ++i) {
        int o = w * 16 + i;
        float acc = 0.0f;
#pragma unroll
        for (int j = 0; j < 8; ++j) {
            int k = lane + (j << 6);
            acc += h1[k] * fw2[o*512 + k];
        }
#pragma unroll
        for (int m = 1; m < 64; m <<= 1) acc += __shfl_xor(acc, m, 64);
        if (lane == 0) h2[o] = fmaxf(acc + fb2[o], 0.0f);
    }
    __syncthreads();
    if (w < 3) {
        float acc = 0.0f;
#pragma unroll
        for (int j = 0; j < 4; ++j) {
            int k = lane + (j << 6);
            acc += h2[k] * fw3[w*256 + k];
        }
#pragma unroll
        for (int m = 1; m < 64; m <<= 1) acc += __shfl_xor(acc, m, 64);
        if (lane == 0) out[b*3 + w] = acc + fb3[w];
    }
}

extern "C" void kernel_launch(void* const* d_in, const int* in_sizes, int n_in,
                              void* d_out, int out_size, void* d_ws, size_t ws_size,
                              hipStream_t stream)
{
    const float* x    = (const float*)d_in[0];
    const int*   far0 = (const int*)  d_in[1];
    const float *w1 = (const float*)d_in[2],  *b1 = (const float*)d_in[3];
    const float *w2 = (const float*)d_in[4],  *b2 = (const float*)d_in[5];
    const float *w3 = (const float*)d_in[6],  *b3 = (const float*)d_in[7];
    const float *w4 = (const float*)d_in[8],  *b4 = (const float*)d_in[9];
    const float *w5 = (const float*)d_in[10], *b5 = (const float*)d_in[11];
    const float *fw1 = (const float*)d_in[12], *fb1 = (const float*)d_in[13];
    const float *fw2 = (const float*)d_in[14], *fb2 = (const float*)d_in[15];
    const float *fw3 = (const float*)d_in[16], *fb3 = (const float*)d_in[17];

    char* ws = (char*)d_ws;
    int*      ccount = (int*)     (ws + OFF_CCOUNT);
    int*      scount = (int*)     (ws + OFF_SCOUNT);
    unsigned* sbits  = (unsigned*)(ws + OFF_SBITS);
    float*    pool   = (float*)   (ws + OFF_POOL);
    int*      clist  = (int*)     (ws + OFF_CLIST);
    float*    h1g    = (float*)   (ws + OFF_H1);
    int*      slist  = (int*)     (ws + OFF_SLIST);

    // workspace zeroing is folded into fps_kernel (one less graph node)
    fps_kernel<<<BN, 512, 0, stream>>>(x, far0, clist, ccount, scount, sbits, pool);
    knn_kernel<<<dim3(NCC/CCH, BN), 1024, 0, stream>>>(x, clist, ccount, sbits, slist, scount);
    mlp_kernel<<<dim3(32, BN, 4), 1024, 0, stream>>>(x, slist, scount,
        w1,b1, w2,b2, w3,b3, w4,b4, w5,b5, pool);
    head1_kernel<<<dim3(4, BN), 1024, 0, stream>>>(pool, fw1, fb1, h1g);
    head2_kernel<<<BN, 1024, 0, stream>>>(h1g, fw2,fb2, fw3,fb3, (float*)d_out);
}

// Round 8
// 184.907 us; speedup vs baseline: 1.0529x; 1.0529x over previous
//
#include <hip/hip_runtime.h>

// Problem constants (fixed by setup_inputs / reference)
#define BN  4       // batch
#define NPT 16384   // points per batch
#define NCC 1024    // FPS centroids (cap on unique orbit length)
#define KNN 32      // neighbors

// KNN select parameters
#define HBINS    2048   // 11-bit level-1 histogram
#define CCH      2      // centroids per chunk-block (keys fit in regs)
#define CAND_CAP 768    // boundary-bin candidate cap (overflow -> exact drill)

// Workspace layout (bytes). Total ~305 KB.
#define OFF_CCOUNT 0                          // BN ints
#define OFF_SCOUNT 64                         // BN ints
#define OFF_SBITS  128                        // BN*(NPT/32) u32 = 8 KB
#define OFF_POOL   (128 + BN*(NPT/32)*4)      // BN*NCC floats = 16 KB
#define OFF_CLIST  (OFF_POOL + BN*NCC*4)      // BN*NCC ints = 16 KB
#define OFF_SLIST  (OFF_CLIST + BN*NCC*4)     // BN*NPT ints = 256 KB

typedef short bf16x8 __attribute__((ext_vector_type(8)));
typedef float f32x4  __attribute__((ext_vector_type(4)));
typedef float f32x2  __attribute__((ext_vector_type(2)));

__device__ __forceinline__ short f2bf(float f) {   // RNE fp32 -> bf16
    unsigned u = __float_as_uint(f);
    return (short)((u + 0x7fffu + ((u >> 16) & 1u)) >> 16);
}
__device__ __forceinline__ bf16x8 cvt8(const float* __restrict__ p) {
    bf16x8 v;
#pragma unroll
    for (int j = 0; j < 8; ++j) v[j] = f2bf(p[j]);
    return v;
}

// ---------------------------------------------------------------------------
// FPS v6: structure = proven v4/v5 (1 barrier/iter, 3-slot rotating packed-u64
// argmax, deferred seen-marking, s_load coords), now 1024 threads with 16
// pts/thread (8 f32x2 pairs, ascending index order preserved) -- halves the
// per-iteration dist-loop on the serial critical path. Also zeroes this
// batch's workspace slices (replaces the memset node). fp contract(off):
// per-element ops bit-identical to the reference __f*_rn sequence.
// ---------------------------------------------------------------------------
__global__ __launch_bounds__(1024) void fps_kernel(const float* __restrict__ x,
    const int* __restrict__ far_init, int* __restrict__ clist, int* __restrict__ ccount,
    int* __restrict__ scount, unsigned* __restrict__ sbits, float* __restrict__ pool)
{
#pragma clang fp contract(off)
    const int b = blockIdx.x, t = threadIdx.x;
    __shared__ __align__(16) unsigned char seen[NPT];
    __shared__ unsigned long long slot[3];

    // ---- workspace zeroing for this batch ----
    if (t < 512) sbits[b*(NPT/32) + t] = 0u;      // 512 u32
    pool[b*NCC + t] = 0.0f;                       // 1024 floats
    if (t == 0) { ccount[b] = 0; scount[b] = 0; }

    const float* xb = x + (size_t)b * NPT * 3;
    // pairs (ia, ia+1024), ia = t + (2r<<10): ascending index order per thread
    f32x2 px[8], py[8], pz[8];
#pragma unroll
    for (int r = 0; r < 8; ++r) {
        int ia = t + ((2*r) << 10), ib = ia + 1024;
        px[r] = f32x2{xb[ia*3+0], xb[ib*3+0]};
        py[r] = f32x2{xb[ia*3+1], xb[ib*3+1]};
        pz[r] = f32x2{xb[ia*3+2], xb[ib*3+2]};
    }
    ((uint4*)seen)[t] = make_uint4(0,0,0,0);      // 1024 * 16B = 16 KB
    if (t == 0) { slot[0] = 0ull; slot[1] = 0ull; slot[2] = 0ull; }
    int prev_bx = far_init[b];                    // uniform (same global read)
    __syncthreads();
    int pbs = __builtin_amdgcn_readfirstlane(prev_bx);
    float cx = xb[pbs*3], cy = xb[pbs*3+1], cz = xb[pbs*3+2];

    int done = 0;
    for (int it = 0; it < NCC-1; ++it) {
        const int p = it % 3;
        const f32x2 cX = {cx, cx}, cY = {cy, cy}, cZ = {cz, cz};
        float best = -1.0f; int bi = 0;
#pragma unroll
        for (int r = 0; r < 8; ++r) {
            f32x2 dx = px[r] - cX;
            f32x2 dy = py[r] - cY;
            f32x2 dz = pz[r] - cZ;
            f32x2 m1 = dx * dx;
            f32x2 m2 = dy * dy;
            f32x2 m3 = dz * dz;
            f32x2 s  = (m1 + m2) + m3;            // exact grouping of reference
            int ia = t + ((2*r) << 10);
            if (s.x > best) { best = s.x; bi = ia; }         // strict >: first max
            if (s.y > best) { best = s.y; bi = ia + 1024; }
        }
#pragma unroll
        for (int m = 1; m < 64; m <<= 1) {
            float od = __shfl_xor(best, m, 64);
            int   oi = __shfl_xor(bi,   m, 64);
            if (od > best || (od == best && oi < bi)) { best = od; bi = oi; }
        }
        if ((t & 63) == 0) {
            unsigned long long pk =
                (((unsigned long long)__float_as_uint(best)) << 32)
                | (unsigned)(NPT - 1 - bi);
            atomicMax(&slot[p], pk);
        }
        if (t == 0) seen[prev_bx] = 1;            // pre-barrier write, no readers now
        __syncthreads();                          // THE barrier
        int bx = NPT - 1 - (int)(unsigned)(slot[p] & 0xFFFFFFFFull);
        if (t == 0) slot[(it + 2) % 3] = 0ull;    // safe: barrier-separated both ways
        if (seen[bx]) { done = 1; break; }        // uniform (stable post-barrier)
        prev_bx = bx;
        int bxs = __builtin_amdgcn_readfirstlane(bx);
        cx = xb[bxs*3]; cy = xb[bxs*3+1]; cz = xb[bxs*3+2];
    }
    if (!done && t == 0) seen[prev_bx] = 1;       // full-length orbit: mark last
    __syncthreads();
    // Emit unique-centroid list (order-free; downstream is set-invariant).
#pragma unroll
    for (int j = 0; j < 16; ++j) {
        int idx = t + (j << 10);
        if (seen[idx]) {
            int pos = atomicAdd(&ccount[b], 1);
            clist[b * NCC + pos] = idx;
        }
    }
}

// ---------------------------------------------------------------------------
// KNN v5: chunk-PARALLEL (proven) with REGISTER-CACHED keys: keys for the
// block's CCH=2 centroids x 16 pts/thread are computed once (sweep 1) and
// reused by sweeps 2 and 3 -- eliminates 2 of 3 x-read+key-recompute passes.
// Values are identical; exact-tau semantics unchanged. Drill-down (rare)
// recomputes from x. Tail-clamped centroid slots (dup tau, set-safe).
// ---------------------------------------------------------------------------
__device__ __forceinline__ unsigned key_of(float px, float py, float pz, float xn,
                                           float cx, float cy, float cz, float cn)
{
    float dot = __fadd_rn(__fadd_rn(__fmul_rn(cx,px), __fmul_rn(cy,py)), __fmul_rn(cz,pz));
    float d2  = __fsub_rn(__fadd_rn(cn, xn), __fmul_rn(2.0f, dot));
    unsigned u = __float_as_uint(d2);
    return u ^ ((u >> 31) ? 0xFFFFFFFFu : 0x80000000u);
}

__device__ __forceinline__ void wave_scan_bins(const unsigned* __restrict__ H,
    int nbins, int rem, int lane, int* __restrict__ out_bin, int* __restrict__ out_below)
{
    int per = nbins >> 6;
    int base = lane * per;
    unsigned part = 0;
    for (int q = 0; q < per; ++q) part += H[base + q];
    unsigned inc = part;
#pragma unroll
    for (int m = 1; m < 64; m <<= 1) {
        unsigned u = __shfl_up(inc, m, 64);
        if (lane >= m) inc += u;
    }
    unsigned exc = inc - part;
    unsigned long long mk = __ballot(exc < (unsigned)rem && inc >= (unsigned)rem);
    int src = __ffsll((long long)mk) - 1;
    if (lane == src) {
        unsigned run = exc; int bb = base;
        for (int q = 0; q < per; ++q) {
            unsigned h = H[base + q];
            if (run + h >= (unsigned)rem) { bb = base + q; break; }
            run += h;
        }
        *out_bin = bb; *out_below = (int)run;
    }
}

__global__ __launch_bounds__(1024) void knn_kernel(const float* __restrict__ x,
    const int* __restrict__ clist, const int* __restrict__ ccount,
    unsigned* __restrict__ sbits, int* __restrict__ slist, int* __restrict__ scount)
{
    const int b = blockIdx.y, t = threadIdx.x;
    const int lane = t & 63, w = t >> 6;
    const int cnt = ccount[b];
    const int cbase = blockIdx.x * CCH;
    if (cbase >= cnt) return;                  // uniform exit, before any barrier
    const float* xb = x + (size_t)b * NPT * 3;

    __shared__ unsigned hist[CCH * HBINS];     // 16 KB
    __shared__ unsigned cand[CCH * CAND_CAP];  // 6 KB
    __shared__ float cpx[CCH], cpy[CCH], cpz[CCH], cpn[CCH];
    __shared__ unsigned candCnt[CCH];
    __shared__ int s_bb[CCH], s_below[CCH], s_rrem[CCH], s_need[CCH], s_pref[CCH];
    __shared__ unsigned s_tau[CCH];
    __shared__ int s_tbin, s_tbelow;

    if (t < CCH) {
        int ci = clist[b * NCC + min(cbase + t, cnt - 1)];   // tail-clamp dup
        float cx = xb[ci*3], cy = xb[ci*3+1], cz = xb[ci*3+2];
        cpx[t] = cx; cpy[t] = cy; cpz[t] = cz;
        cpn[t] = __fadd_rn(__fadd_rn(__fmul_rn(cx,cx), __fmul_rn(cy,cy)), __fmul_rn(cz,cz));
        candCnt[t] = 0;
    }
    for (int i = t; i < CCH * HBINS; i += 1024) hist[i] = 0;
    __syncthreads();

    // Sweep 1: compute keys ONCE into registers + build histograms.
    unsigned keys[NPT/1024][CCH];              // 16 x 2 u32 = 32 VGPRs
#pragma unroll
    for (int j = 0; j < NPT/1024; ++j) {
        int i = t + (j << 10);
        float px = xb[i*3], py = xb[i*3+1], pz = xb[i*3+2];
        float xn = __fadd_rn(__fadd_rn(__fmul_rn(px,px), __fmul_rn(py,py)), __fmul_rn(pz,pz));
#pragma unroll
        for (int c = 0; c < CCH; ++c) {
            unsigned key = key_of(px,py,pz,xn, cpx[c],cpy[c],cpz[c],cpn[c]);
            keys[j][c] = key;
            atomicAdd(&hist[c*HBINS + (key >> 21)], 1u);
        }
    }
    __syncthreads();

    if (w < CCH)
        wave_scan_bins(&hist[w*HBINS], HBINS, KNN, lane, &s_bb[w], &s_below[w]);
    __syncthreads();
    if (t < CCH) s_rrem[t] = KNN - s_below[t];
    __syncthreads();

    // Sweep 2 (registers only): collect candidate keys in boundary bins.
#pragma unroll
    for (int j = 0; j < NPT/1024; ++j) {
#pragma unroll
        for (int c = 0; c < CCH; ++c) {
            unsigned key = keys[j][c];
            if ((int)(key >> 21) == s_bb[c]) {
                unsigned pos = atomicAdd(&candCnt[c], 1u);
                if (pos < CAND_CAP) cand[c*CAND_CAP + pos] = key;
            }
        }
    }
    __syncthreads();

    // Exact tau: rank-select (rrem-th smallest with multiplicity) per wave.
    if (w < CCH) {
        unsigned cc = candCnt[w];
        if (cc <= CAND_CAP) {
            int r = s_rrem[w] - 1;
            const unsigned* C = &cand[w*CAND_CAP];
            for (int idx = lane; idx < (int)cc; idx += 64) {
                unsigned k = C[idx]; int rank = 0;
                for (int q = 0; q < (int)cc; ++q) {
                    unsigned kq = C[q];
                    rank += (kq < k || (kq == k && q < idx)) ? 1 : 0;
                }
                if (rank == r) s_tau[w] = k;
            }
            if (lane == 0) s_need[w] = 0;
        } else if (lane == 0) s_need[w] = 1;
    }
    __syncthreads();

    // Rare exact drill-down for overflowed boundary bins (guaranteed exact).
    for (int c = 0; c < CCH; ++c) {
        if (s_need[c]) {
            const float cx = cpx[c], cy = cpy[c], cz = cpz[c], cn = cpn[c];
            for (int i = t; i < HBINS; i += 1024) hist[i] = 0;
            __syncthreads();
            for (int j = 0; j < NPT/1024; ++j) {
                int i = t + (j << 10);
                float px = xb[i*3], py = xb[i*3+1], pz = xb[i*3+2];
                float xn = __fadd_rn(__fadd_rn(__fmul_rn(px,px), __fmul_rn(py,py)), __fmul_rn(pz,pz));
                unsigned key = key_of(px,py,pz,xn, cx,cy,cz,cn);
                if ((int)(key >> 21) == s_bb[c]) atomicAdd(&hist[(key >> 10) & 2047u], 1u);
            }
            __syncthreads();
            if (w == 0) wave_scan_bins(hist, HBINS, s_rrem[c], lane, &s_tbin, &s_tbelow);
            __syncthreads();
            if (t == 0) { s_pref[c] = (s_bb[c] << 11) | s_tbin; s_rrem[c] -= s_tbelow; }
            __syncthreads();
            for (int i = t; i < 1024; i += 1024) hist[i] = 0;
            __syncthreads();
            for (int j = 0; j < NPT/1024; ++j) {
                int i = t + (j << 10);
                float px = xb[i*3], py = xb[i*3+1], pz = xb[i*3+2];
                float xn = __fadd_rn(__fadd_rn(__fmul_rn(px,px), __fmul_rn(py,py)), __fmul_rn(pz,pz));
                unsigned key = key_of(px,py,pz,xn, cx,cy,cz,cn);
                if ((int)(key >> 10) == s_pref[c]) atomicAdd(&hist[key & 1023u], 1u);
            }
            __syncthreads();
            if (w == 0) wave_scan_bins(hist, 1024, s_rrem[c], lane, &s_tbin, &s_tbelow);
            __syncthreads();
            if (t == 0) s_tau[c] = (((unsigned)s_pref[c]) << 10) | (unsigned)s_tbin;
            __syncthreads();
        }
    }
    __syncthreads();

    // Sweep 3 (registers only): union-mark + build compacted list (deduped).
#pragma unroll
    for (int j = 0; j < NPT/1024; ++j) {
        int i = t + (j << 10);
        bool sel = false;
#pragma unroll
        for (int c = 0; c < CCH; ++c) sel |= (keys[j][c] <= s_tau[c]);
        if (sel) {
            unsigned bit = 1u << (i & 31);
            unsigned old = atomicOr(&sbits[b*(NPT/32) + (i >> 5)], bit);
            if (!(old & bit)) {
                int pos = atomicAdd(&scount[b], 1);
                slist[b * NPT + pos] = i;
            }
        }
    }
}

// ---------------------------------------------------------------------------
// MLP v4 (proven R6): MFMA 16x16x32 bf16, weights persistent in VGPR B-frags.
// ---------------------------------------------------------------------------
#define MFMA16(a, bfr, c) __builtin_amdgcn_mfma_f32_16x16x32_bf16(a, bfr, c, 0, 0, 0)

__global__ __launch_bounds__(1024) void mlp_kernel(const float* __restrict__ x,
    const int* __restrict__ sel_list, const int* __restrict__ sel_count,
    const float* __restrict__ w1, const float* __restrict__ b1,
    const float* __restrict__ w2, const float* __restrict__ b2,
    const float* __restrict__ w3, const float* __restrict__ b3,
    const float* __restrict__ w4, const float* __restrict__ b4,
    const float* __restrict__ w5, const float* __restrict__ b5,
    float* __restrict__ pool)
{
    const int b = blockIdx.y, z = blockIdx.z, t = threadIdx.x;
    const int cnt = sel_count[b];
    if ((blockIdx.x << 6) >= cnt) return;      // uniform, before any barrier
    const int lane = t & 63;
    const int w    = __builtin_amdgcn_readfirstlane(t >> 6);  // 0..15
    const int m    = lane & 15, quad = lane >> 4;

    __shared__ __align__(16) short A1[64 * 72];    // 9 KB
    __shared__ __align__(16) short A2[64 * 72];    // 9 KB
    __shared__ __align__(16) short A3[64 * 136];   // 17 KB
    __shared__ float sx[3 * 64];

    // ---- persistent weight fragments (once per block) ----
    const int ocA = (w >> 2) * 16 + m;             // L2/L3 oc (wave>>2 = oc_tile)
    bf16x8 bw2[2], bw3[2], bw4[2][2], bw5[4];
#pragma unroll
    for (int ks = 0; ks < 2; ++ks) {
        bw2[ks] = cvt8(w2 + ocA*64 + ks*32 + quad*8);
        bw3[ks] = cvt8(w3 + ocA*64 + ks*32 + quad*8);
    }
    int oc4i[2];
#pragma unroll
    for (int r2 = 0; r2 < 2; ++r2) {
        oc4i[r2] = ((w >> 2) + 4*r2) * 16 + m;
#pragma unroll
        for (int ks = 0; ks < 2; ++ks)
            bw4[r2][ks] = cvt8(w4 + oc4i[r2]*64 + ks*32 + quad*8);
    }
    const int oc5 = z*256 + w*16 + m;
#pragma unroll
    for (int ks = 0; ks < 4; ++ks)
        bw5[ks] = cvt8(w5 + oc5*128 + ks*32 + quad*8);
    const float bias2 = b2[ocA], bias3 = b3[ocA];
    const float bias4_0 = b4[oc4i[0]], bias4_1 = b4[oc4i[1]];
    const float bias5 = b5[oc5];
    float w1v[4][3], b1v[4];
#pragma unroll
    for (int i = 0; i < 4; ++i) {
        int oc = w*4 + i;
        w1v[i][0] = w1[oc*3+0]; w1v[i][1] = w1[oc*3+1]; w1v[i][2] = w1[oc*3+2];
        b1v[i] = b1[oc];
    }
    const int pt0 = (w & 3) * 16;                  // pt tile for L2/L3/L4

    for (int base = blockIdx.x << 6; base < cnt; base += (32 << 6)) {
        const int npts = min(64, cnt - base);
        __syncthreads();                            // prev tile fully consumed
        if (t < 64) {
            int idx = sel_list[b * NPT + base + min(t, npts - 1)];  // pad = dup last
            const float* xp = x + ((size_t)b * NPT + idx) * 3;
            sx[t] = xp[0]; sx[64 + t] = xp[1]; sx[128 + t] = xp[2];
        }
        __syncthreads();
        {   // L1: 3->64, fp32 VALU, write bf16 [pt][72]
            float x0 = sx[lane], x1 = sx[64 + lane], x2 = sx[128 + lane];
#pragma unroll
            for (int i = 0; i < 4; ++i) {
                float acc = fmaf(x2, w1v[i][2], fmaf(x1, w1v[i][1],
                             fmaf(x0, w1v[i][0], b1v[i])));
                A1[lane*72 + w*4 + i] = f2bf(fmaxf(acc, 0.0f));
            }
        }
        __syncthreads();
        {   // L2: A1 -> A2 (64->64)
            bf16x8 a0 = *(const bf16x8*)&A1[(pt0 + m)*72 + quad*8];
            bf16x8 a1 = *(const bf16x8*)&A1[(pt0 + m)*72 + 32 + quad*8];
            f32x4 d = {0.f, 0.f, 0.f, 0.f};
            d = MFMA16(a0, bw2[0], d);
            d = MFMA16(a1, bw2[1], d);
#pragma unroll
            for (int r = 0; r < 4; ++r)
                A2[(pt0 + quad*4 + r)*72 + ocA] = f2bf(fmaxf(d[r] + bias2, 0.0f));
        }
        __syncthreads();
        {   // L3: A2 -> A1 (64->64)
            bf16x8 a0 = *(const bf16x8*)&A2[(pt0 + m)*72 + quad*8];
            bf16x8 a1 = *(const bf16x8*)&A2[(pt0 + m)*72 + 32 + quad*8];
            f32x4 d = {0.f, 0.f, 0.f, 0.f};
            d = MFMA16(a0, bw3[0], d);
            d = MFMA16(a1, bw3[1], d);
#pragma unroll
            for (int r = 0; r < 4; ++r)
                A1[(pt0 + quad*4 + r)*72 + ocA] = f2bf(fmaxf(d[r] + bias3, 0.0f));
        }
        __syncthreads();
        {   // L4: A1 -> A3 (64->128), 2 oc-tiles per wave
            bf16x8 a0 = *(const bf16x8*)&A1[(pt0 + m)*72 + quad*8];
            bf16x8 a1 = *(const bf16x8*)&A1[(pt0 + m)*72 + 32 + quad*8];
#pragma unroll
            for (int r2 = 0; r2 < 2; ++r2) {
                f32x4 d = {0.f, 0.f, 0.f, 0.f};
                d = MFMA16(a0, bw4[r2][0], d);
                d = MFMA16(a1, bw4[r2][1], d);
                float bs = r2 ? bias4_1 : bias4_0;
#pragma unroll
                for (int r = 0; r < 4; ++r)
                    A3[(pt0 + quad*4 + r)*136 + oc4i[r2]] = f2bf(fmaxf(d[r] + bs, 0.0f));
            }
        }
        __syncthreads();
        {   // L5 (128 -> this block's 256-oc slice) + max-pool
            float vm = 0.0f;                        // relu outputs >= 0
#pragma unroll
            for (int pt4 = 0; pt4 < 4; ++pt4) {
                const int q0 = pt4 * 16;
                f32x4 d = {0.f, 0.f, 0.f, 0.f};
#pragma unroll
                for (int ks = 0; ks < 4; ++ks) {
                    bf16x8 a = *(const bf16x8*)&A3[(q0 + m)*136 + ks*32 + quad*8];
                    d = MFMA16(a, bw5[ks], d);
                }
#pragma unroll
                for (int r = 0; r < 4; ++r)
                    vm = fmaxf(vm, fmaxf(d[r] + bias5, 0.0f));
            }
            vm = fmaxf(vm, __shfl_xor(vm, 16, 64));
            vm = fmaxf(vm, __shfl_xor(vm, 32, 64));
            if (lane < 16)
                atomicMax((int*)&pool[b*NCC + z*256 + w*16 + lane], __float_as_int(vm));
        }
    }
}

// ---------------------------------------------------------------------------
// FC head FUSED (R2-proven shape): FC1+FC2+FC3 in one block/batch.
// Wave-per-output, lanes split K (coalesced weight rows), butterfly reduce.
// ---------------------------------------------------------------------------
__global__ __launch_bounds__(1024) void head_kernel(const float* __restrict__ pool,
    const float* __restrict__ fw1, const float* __restrict__ fb1,
    const float* __restrict__ fw2, const float* __restrict__ fb2,
    const float* __restrict__ fw3, const float* __restrict__ fb3,
    float* __restrict__ out)
{
    const int b = blockIdx.x, t = threadIdx.x;
    const int lane = t & 63;
    const int w = __builtin_amdgcn_readfirstlane(t >> 6);  // 0..15
    __shared__ float g[1024], h1[512], h2[256];
    g[t] = pool[b*NCC + t];
    __syncthreads();
    // FC1: 1024 -> 512 relu. 32 outputs per wave.
#pragma unroll
    for (int i = 0; i < 32; ++i) {
        int o = w * 32 + i;
        float acc = 0.0f;
#pragma unroll
        for (int j = 0; j < 16; ++j) {
            int k = lane + (j << 6);
            acc += g[k] * fw1[o*1024 + k];
        }
#pragma unroll
        for (int m = 1; m < 64; m <<= 1) acc += __shfl_xor(acc, m, 64);
        if (lane == 0) h1[o] = fmaxf(acc + fb1[o], 0.0f);
    }
    __syncthreads();
    // FC2: 512 -> 256 relu. 16 outputs per wave.
#pragma unroll
    for (int i = 0; i < 16; ++i) {
        int o = w * 16 + i;
        float acc = 0.0f;
#pragma unroll
        for (int j = 0; j < 8; ++j) {
            int k = lane + (j << 6);
            acc += h1[k] * fw2[o*512 + k];
        }
#pragma unroll
        for (int m = 1; m < 64; m <<= 1) acc += __shfl_xor(acc, m, 64);
        if (lane == 0) h2[o] = fmaxf(acc + fb2[o], 0.0f);
    }
    __syncthreads();
    // FC3: 256 -> 3 (no relu). Waves 0..2.
    if (w < 3) {
        float acc = 0.0f;
#pragma unroll
        for (int j = 0; j < 4; ++j) {
            int k = lane + (j << 6);
            acc += h2[k] * fw3[w*256 + k];
        }
#pragma unroll
        for (int m = 1; m < 64; m <<= 1) acc += __shfl_xor(acc, m, 64);
        if (lane == 0) out[b*3 + w] = acc + fb3[w];
    }
}

extern "C" void kernel_launch(void* const* d_in, const int* in_sizes, int n_in,
                              void* d_out, int out_size, void* d_ws, size_t ws_size,
                              hipStream_t stream)
{
    const float* x    = (const float*)d_in[0];
    const int*   far0 = (const int*)  d_in[1];
    const float *w1 = (const float*)d_in[2],  *b1 = (const float*)d_in[3];
    const float *w2 = (const float*)d_in[4],  *b2 = (const float*)d_in[5];
    const float *w3 = (const float*)d_in[6],  *b3 = (const float*)d_in[7];
    const float *w4 = (const float*)d_in[8],  *b4 = (const float*)d_in[9];
    const float *w5 = (const float*)d_in[10], *b5 = (const float*)d_in[11];
    const float *fw1 = (const float*)d_in[12], *fb1 = (const float*)d_in[13];
    const float *fw2 = (const float*)d_in[14], *fb2 = (const float*)d_in[15];
    const float *fw3 = (const float*)d_in[16], *fb3 = (const float*)d_in[17];

    char* ws = (char*)d_ws;
    int*      ccount = (int*)     (ws + OFF_CCOUNT);
    int*      scount = (int*)     (ws + OFF_SCOUNT);
    unsigned* sbits  = (unsigned*)(ws + OFF_SBITS);
    float*    pool   = (float*)   (ws + OFF_POOL);
    int*      clist  = (int*)     (ws + OFF_CLIST);
    int*      slist  = (int*)     (ws + OFF_SLIST);

    // workspace zeroing is folded into fps_kernel
    fps_kernel<<<BN, 1024, 0, stream>>>(x, far0, clist, ccount, scount, sbits, pool);
    knn_kernel<<<dim3(NCC/CCH, BN), 1024, 0, stream>>>(x, clist, ccount, sbits, slist, scount);
    mlp_kernel<<<dim3(32, BN, 4), 1024, 0, stream>>>(x, slist, scount,
        w1,b1, w2,b2, w3,b3, w4,b4, w5,b5, pool);
    head_kernel<<<BN, 1024, 0, stream>>>(pool, fw1,fb1, fw2,fb2, fw3,fb3, (float*)d_out);
}

// Round 9
// 159.962 us; speedup vs baseline: 1.2171x; 1.1559x over previous
//
#include <hip/hip_runtime.h>

// Problem constants (fixed by setup_inputs / reference)
#define BN  4       // batch
#define NPT 16384   // points per batch
#define NCC 1024    // FPS centroids (cap on unique orbit length)
#define KNN 32      // neighbors

// KNN select parameters
#define HBINS    2048   // 11-bit level-1 histogram
#define CCH      2      // centroids per chunk-block (keys fit in regs)
#define CAND_CAP 768    // boundary-bin candidate cap (overflow -> exact drill)

// Workspace layout (bytes). Total ~310 KB.
#define OFF_CCOUNT 0                          // BN ints
#define OFF_SCOUNT 64                         // BN ints
#define OFF_SBITS  128                        // BN*(NPT/32) u32 = 8 KB
#define OFF_POOL   (128 + BN*(NPT/32)*4)      // BN*NCC floats = 16 KB
#define OFF_CLIST  (OFF_POOL + BN*NCC*4)      // BN*NCC ints = 16 KB
#define OFF_H1     (OFF_CLIST + BN*NCC*4)     // BN*512 floats = 8 KB
#define OFF_H2     (OFF_H1 + BN*512*4)        // BN*256 floats = 4 KB
#define OFF_SLIST  (OFF_H2 + BN*256*4)        // BN*NPT ints = 256 KB

typedef short bf16x8 __attribute__((ext_vector_type(8)));
typedef float f32x4  __attribute__((ext_vector_type(4)));
typedef float f32x2  __attribute__((ext_vector_type(2)));

__device__ __forceinline__ short f2bf(float f) {   // RNE fp32 -> bf16
    unsigned u = __float_as_uint(f);
    return (short)((u + 0x7fffu + ((u >> 16) & 1u)) >> 16);
}
__device__ __forceinline__ bf16x8 cvt8(const float* __restrict__ p) {
    bf16x8 v;
#pragma unroll
    for (int j = 0; j < 8; ++j) v[j] = f2bf(p[j]);
    return v;
}

// ---------------------------------------------------------------------------
// FPS v6 (proven R8): 1024 threads, 16 pts/thread (f32x2 pairs), 1 barrier/
// iter, 3-slot rotating packed-u64 argmax, deferred seen-marking, s_load
// coords, workspace zeroing folded in. absmax 0.0.
// ---------------------------------------------------------------------------
__global__ __launch_bounds__(1024) void fps_kernel(const float* __restrict__ x,
    const int* __restrict__ far_init, int* __restrict__ clist, int* __restrict__ ccount,
    int* __restrict__ scount, unsigned* __restrict__ sbits, float* __restrict__ pool)
{
#pragma clang fp contract(off)
    const int b = blockIdx.x, t = threadIdx.x;
    __shared__ __align__(16) unsigned char seen[NPT];
    __shared__ unsigned long long slot[3];

    // ---- workspace zeroing for this batch ----
    if (t < 512) sbits[b*(NPT/32) + t] = 0u;      // 512 u32
    pool[b*NCC + t] = 0.0f;                       // 1024 floats
    if (t == 0) { ccount[b] = 0; scount[b] = 0; }

    const float* xb = x + (size_t)b * NPT * 3;
    f32x2 px[8], py[8], pz[8];
#pragma unroll
    for (int r = 0; r < 8; ++r) {
        int ia = t + ((2*r) << 10), ib = ia + 1024;
        px[r] = f32x2{xb[ia*3+0], xb[ib*3+0]};
        py[r] = f32x2{xb[ia*3+1], xb[ib*3+1]};
        pz[r] = f32x2{xb[ia*3+2], xb[ib*3+2]};
    }
    ((uint4*)seen)[t] = make_uint4(0,0,0,0);      // 1024 * 16B = 16 KB
    if (t == 0) { slot[0] = 0ull; slot[1] = 0ull; slot[2] = 0ull; }
    int prev_bx = far_init[b];                    // uniform (same global read)
    __syncthreads();
    int pbs = __builtin_amdgcn_readfirstlane(prev_bx);
    float cx = xb[pbs*3], cy = xb[pbs*3+1], cz = xb[pbs*3+2];

    int done = 0;
    for (int it = 0; it < NCC-1; ++it) {
        const int p = it % 3;
        const f32x2 cX = {cx, cx}, cY = {cy, cy}, cZ = {cz, cz};
        float best = -1.0f; int bi = 0;
#pragma unroll
        for (int r = 0; r < 8; ++r) {
            f32x2 dx = px[r] - cX;
            f32x2 dy = py[r] - cY;
            f32x2 dz = pz[r] - cZ;
            f32x2 m1 = dx * dx;
            f32x2 m2 = dy * dy;
            f32x2 m3 = dz * dz;
            f32x2 s  = (m1 + m2) + m3;            // exact grouping of reference
            int ia = t + ((2*r) << 10);
            if (s.x > best) { best = s.x; bi = ia; }         // strict >: first max
            if (s.y > best) { best = s.y; bi = ia + 1024; }
        }
#pragma unroll
        for (int m = 1; m < 64; m <<= 1) {
            float od = __shfl_xor(best, m, 64);
            int   oi = __shfl_xor(bi,   m, 64);
            if (od > best || (od == best && oi < bi)) { best = od; bi = oi; }
        }
        if ((t & 63) == 0) {
            unsigned long long pk =
                (((unsigned long long)__float_as_uint(best)) << 32)
                | (unsigned)(NPT - 1 - bi);
            atomicMax(&slot[p], pk);
        }
        if (t == 0) seen[prev_bx] = 1;            // pre-barrier write, no readers now
        __syncthreads();                          // THE barrier
        int bx = NPT - 1 - (int)(unsigned)(slot[p] & 0xFFFFFFFFull);
        if (t == 0) slot[(it + 2) % 3] = 0ull;    // safe: barrier-separated both ways
        if (seen[bx]) { done = 1; break; }        // uniform (stable post-barrier)
        prev_bx = bx;
        int bxs = __builtin_amdgcn_readfirstlane(bx);
        cx = xb[bxs*3]; cy = xb[bxs*3+1]; cz = xb[bxs*3+2];
    }
    if (!done && t == 0) seen[prev_bx] = 1;       // full-length orbit: mark last
    __syncthreads();
#pragma unroll
    for (int j = 0; j < 16; ++j) {
        int idx = t + (j << 10);
        if (seen[idx]) {
            int pos = atomicAdd(&ccount[b], 1);
            clist[b * NCC + pos] = idx;
        }
    }
}

// ---------------------------------------------------------------------------
// KNN v5 (proven R8): chunk-parallel, register-cached keys (compute once,
// reuse in sweeps 2/3). Exact tau; drill-down recomputes. Tail-clamp dup.
// ---------------------------------------------------------------------------
__device__ __forceinline__ unsigned key_of(float px, float py, float pz, float xn,
                                           float cx, float cy, float cz, float cn)
{
    float dot = __fadd_rn(__fadd_rn(__fmul_rn(cx,px), __fmul_rn(cy,py)), __fmul_rn(cz,pz));
    float d2  = __fsub_rn(__fadd_rn(cn, xn), __fmul_rn(2.0f, dot));
    unsigned u = __float_as_uint(d2);
    return u ^ ((u >> 31) ? 0xFFFFFFFFu : 0x80000000u);
}

__device__ __forceinline__ void wave_scan_bins(const unsigned* __restrict__ H,
    int nbins, int rem, int lane, int* __restrict__ out_bin, int* __restrict__ out_below)
{
    int per = nbins >> 6;
    int base = lane * per;
    unsigned part = 0;
    for (int q = 0; q < per; ++q) part += H[base + q];
    unsigned inc = part;
#pragma unroll
    for (int m = 1; m < 64; m <<= 1) {
        unsigned u = __shfl_up(inc, m, 64);
        if (lane >= m) inc += u;
    }
    unsigned exc = inc - part;
    unsigned long long mk = __ballot(exc < (unsigned)rem && inc >= (unsigned)rem);
    int src = __ffsll((long long)mk) - 1;
    if (lane == src) {
        unsigned run = exc; int bb = base;
        for (int q = 0; q < per; ++q) {
            unsigned h = H[base + q];
            if (run + h >= (unsigned)rem) { bb = base + q; break; }
            run += h;
        }
        *out_bin = bb; *out_below = (int)run;
    }
}

__global__ __launch_bounds__(1024) void knn_kernel(const float* __restrict__ x,
    const int* __restrict__ clist, const int* __restrict__ ccount,
    unsigned* __restrict__ sbits, int* __restrict__ slist, int* __restrict__ scount)
{
    const int b = blockIdx.y, t = threadIdx.x;
    const int lane = t & 63, w = t >> 6;
    const int cnt = ccount[b];
    const int cbase = blockIdx.x * CCH;
    if (cbase >= cnt) return;                  // uniform exit, before any barrier
    const float* xb = x + (size_t)b * NPT * 3;

    __shared__ unsigned hist[CCH * HBINS];     // 16 KB
    __shared__ unsigned cand[CCH * CAND_CAP];  // 6 KB
    __shared__ float cpx[CCH], cpy[CCH], cpz[CCH], cpn[CCH];
    __shared__ unsigned candCnt[CCH];
    __shared__ int s_bb[CCH], s_below[CCH], s_rrem[CCH], s_need[CCH], s_pref[CCH];
    __shared__ unsigned s_tau[CCH];
    __shared__ int s_tbin, s_tbelow;

    if (t < CCH) {
        int ci = clist[b * NCC + min(cbase + t, cnt - 1)];   // tail-clamp dup
        float cx = xb[ci*3], cy = xb[ci*3+1], cz = xb[ci*3+2];
        cpx[t] = cx; cpy[t] = cy; cpz[t] = cz;
        cpn[t] = __fadd_rn(__fadd_rn(__fmul_rn(cx,cx), __fmul_rn(cy,cy)), __fmul_rn(cz,cz));
        candCnt[t] = 0;
    }
    for (int i = t; i < CCH * HBINS; i += 1024) hist[i] = 0;
    __syncthreads();

    // Sweep 1: compute keys ONCE into registers + build histograms.
    unsigned keys[NPT/1024][CCH];              // 16 x 2 u32 = 32 VGPRs
#pragma unroll
    for (int j = 0; j < NPT/1024; ++j) {
        int i = t + (j << 10);
        float px = xb[i*3], py = xb[i*3+1], pz = xb[i*3+2];
        float xn = __fadd_rn(__fadd_rn(__fmul_rn(px,px), __fmul_rn(py,py)), __fmul_rn(pz,pz));
#pragma unroll
        for (int c = 0; c < CCH; ++c) {
            unsigned key = key_of(px,py,pz,xn, cpx[c],cpy[c],cpz[c],cpn[c]);
            keys[j][c] = key;
            atomicAdd(&hist[c*HBINS + (key >> 21)], 1u);
        }
    }
    __syncthreads();

    if (w < CCH)
        wave_scan_bins(&hist[w*HBINS], HBINS, KNN, lane, &s_bb[w], &s_below[w]);
    __syncthreads();
    if (t < CCH) s_rrem[t] = KNN - s_below[t];
    __syncthreads();

    // Sweep 2 (registers only): collect candidate keys in boundary bins.
#pragma unroll
    for (int j = 0; j < NPT/1024; ++j) {
#pragma unroll
        for (int c = 0; c < CCH; ++c) {
            unsigned key = keys[j][c];
            if ((int)(key >> 21) == s_bb[c]) {
                unsigned pos = atomicAdd(&candCnt[c], 1u);
                if (pos < CAND_CAP) cand[c*CAND_CAP + pos] = key;
            }
        }
    }
    __syncthreads();

    // Exact tau: rank-select (rrem-th smallest with multiplicity) per wave.
    if (w < CCH) {
        unsigned cc = candCnt[w];
        if (cc <= CAND_CAP) {
            int r = s_rrem[w] - 1;
            const unsigned* C = &cand[w*CAND_CAP];
            for (int idx = lane; idx < (int)cc; idx += 64) {
                unsigned k = C[idx]; int rank = 0;
                for (int q = 0; q < (int)cc; ++q) {
                    unsigned kq = C[q];
                    rank += (kq < k || (kq == k && q < idx)) ? 1 : 0;
                }
                if (rank == r) s_tau[w] = k;
            }
            if (lane == 0) s_need[w] = 0;
        } else if (lane == 0) s_need[w] = 1;
    }
    __syncthreads();

    // Rare exact drill-down for overflowed boundary bins (guaranteed exact).
    for (int c = 0; c < CCH; ++c) {
        if (s_need[c]) {
            const float cx = cpx[c], cy = cpy[c], cz = cpz[c], cn = cpn[c];
            for (int i = t; i < HBINS; i += 1024) hist[i] = 0;
            __syncthreads();
            for (int j = 0; j < NPT/1024; ++j) {
                int i = t + (j << 10);
                float px = xb[i*3], py = xb[i*3+1], pz = xb[i*3+2];
                float xn = __fadd_rn(__fadd_rn(__fmul_rn(px,px), __fmul_rn(py,py)), __fmul_rn(pz,pz));
                unsigned key = key_of(px,py,pz,xn, cx,cy,cz,cn);
                if ((int)(key >> 21) == s_bb[c]) atomicAdd(&hist[(key >> 10) & 2047u], 1u);
            }
            __syncthreads();
            if (w == 0) wave_scan_bins(hist, HBINS, s_rrem[c], lane, &s_tbin, &s_tbelow);
            __syncthreads();
            if (t == 0) { s_pref[c] = (s_bb[c] << 11) | s_tbin; s_rrem[c] -= s_tbelow; }
            __syncthreads();
            for (int i = t; i < 1024; i += 1024) hist[i] = 0;
            __syncthreads();
            for (int j = 0; j < NPT/1024; ++j) {
                int i = t + (j << 10);
                float px = xb[i*3], py = xb[i*3+1], pz = xb[i*3+2];
                float xn = __fadd_rn(__fadd_rn(__fmul_rn(px,px), __fmul_rn(py,py)), __fmul_rn(pz,pz));
                unsigned key = key_of(px,py,pz,xn, cx,cy,cz,cn);
                if ((int)(key >> 10) == s_pref[c]) atomicAdd(&hist[key & 1023u], 1u);
            }
            __syncthreads();
            if (w == 0) wave_scan_bins(hist, 1024, s_rrem[c], lane, &s_tbin, &s_tbelow);
            __syncthreads();
            if (t == 0) s_tau[c] = (((unsigned)s_pref[c]) << 10) | (unsigned)s_tbin;
            __syncthreads();
        }
    }
    __syncthreads();

    // Sweep 3 (registers only): union-mark + build compacted list (deduped).
#pragma unroll
    for (int j = 0; j < NPT/1024; ++j) {
        int i = t + (j << 10);
        bool sel = false;
#pragma unroll
        for (int c = 0; c < CCH; ++c) sel |= (keys[j][c] <= s_tau[c]);
        if (sel) {
            unsigned bit = 1u << (i & 31);
            unsigned old = atomicOr(&sbits[b*(NPT/32) + (i >> 5)], bit);
            if (!(old & bit)) {
                int pos = atomicAdd(&scount[b], 1);
                slist[b * NPT + pos] = i;
            }
        }
    }
}

// ---------------------------------------------------------------------------
// MLP v4 (proven R6): MFMA 16x16x32 bf16, weights persistent in VGPR B-frags.
// ---------------------------------------------------------------------------
#define MFMA16(a, bfr, c) __builtin_amdgcn_mfma_f32_16x16x32_bf16(a, bfr, c, 0, 0, 0)

__global__ __launch_bounds__(1024) void mlp_kernel(const float* __restrict__ x,
    const int* __restrict__ sel_list, const int* __restrict__ sel_count,
    const float* __restrict__ w1, const float* __restrict__ b1,
    const float* __restrict__ w2, const float* __restrict__ b2,
    const float* __restrict__ w3, const float* __restrict__ b3,
    const float* __restrict__ w4, const float* __restrict__ b4,
    const float* __restrict__ w5, const float* __restrict__ b5,
    float* __restrict__ pool)
{
    const int b = blockIdx.y, z = blockIdx.z, t = threadIdx.x;
    const int cnt = sel_count[b];
    if ((blockIdx.x << 6) >= cnt) return;      // uniform, before any barrier
    const int lane = t & 63;
    const int w    = __builtin_amdgcn_readfirstlane(t >> 6);  // 0..15
    const int m    = lane & 15, quad = lane >> 4;

    __shared__ __align__(16) short A1[64 * 72];    // 9 KB
    __shared__ __align__(16) short A2[64 * 72];    // 9 KB
    __shared__ __align__(16) short A3[64 * 136];   // 17 KB
    __shared__ float sx[3 * 64];

    const int ocA = (w >> 2) * 16 + m;             // L2/L3 oc (wave>>2 = oc_tile)
    bf16x8 bw2[2], bw3[2], bw4[2][2], bw5[4];
#pragma unroll
    for (int ks = 0; ks < 2; ++ks) {
        bw2[ks] = cvt8(w2 + ocA*64 + ks*32 + quad*8);
        bw3[ks] = cvt8(w3 + ocA*64 + ks*32 + quad*8);
    }
    int oc4i[2];
#pragma unroll
    for (int r2 = 0; r2 < 2; ++r2) {
        oc4i[r2] = ((w >> 2) + 4*r2) * 16 + m;
#pragma unroll
        for (int ks = 0; ks < 2; ++ks)
            bw4[r2][ks] = cvt8(w4 + oc4i[r2]*64 + ks*32 + quad*8);
    }
    const int oc5 = z*256 + w*16 + m;
#pragma unroll
    for (int ks = 0; ks < 4; ++ks)
        bw5[ks] = cvt8(w5 + oc5*128 + ks*32 + quad*8);
    const float bias2 = b2[ocA], bias3 = b3[ocA];
    const float bias4_0 = b4[oc4i[0]], bias4_1 = b4[oc4i[1]];
    const float bias5 = b5[oc5];
    float w1v[4][3], b1v[4];
#pragma unroll
    for (int i = 0; i < 4; ++i) {
        int oc = w*4 + i;
        w1v[i][0] = w1[oc*3+0]; w1v[i][1] = w1[oc*3+1]; w1v[i][2] = w1[oc*3+2];
        b1v[i] = b1[oc];
    }
    const int pt0 = (w & 3) * 16;                  // pt tile for L2/L3/L4

    for (int base = blockIdx.x << 6; base < cnt; base += (32 << 6)) {
        const int npts = min(64, cnt - base);
        __syncthreads();                            // prev tile fully consumed
        if (t < 64) {
            int idx = sel_list[b * NPT + base + min(t, npts - 1)];  // pad = dup last
            const float* xp = x + ((size_t)b * NPT + idx) * 3;
            sx[t] = xp[0]; sx[64 + t] = xp[1]; sx[128 + t] = xp[2];
        }
        __syncthreads();
        {   // L1: 3->64, fp32 VALU, write bf16 [pt][72]
            float x0 = sx[lane], x1 = sx[64 + lane], x2 = sx[128 + lane];
#pragma unroll
            for (int i = 0; i < 4; ++i) {
                float acc = fmaf(x2, w1v[i][2], fmaf(x1, w1v[i][1],
                             fmaf(x0, w1v[i][0], b1v[i])));
                A1[lane*72 + w*4 + i] = f2bf(fmaxf(acc, 0.0f));
            }
        }
        __syncthreads();
        {   // L2: A1 -> A2 (64->64)
            bf16x8 a0 = *(const bf16x8*)&A1[(pt0 + m)*72 + quad*8];
            bf16x8 a1 = *(const bf16x8*)&A1[(pt0 + m)*72 + 32 + quad*8];
            f32x4 d = {0.f, 0.f, 0.f, 0.f};
            d = MFMA16(a0, bw2[0], d);
            d = MFMA16(a1, bw2[1], d);
#pragma unroll
            for (int r = 0; r < 4; ++r)
                A2[(pt0 + quad*4 + r)*72 + ocA] = f2bf(fmaxf(d[r] + bias2, 0.0f));
        }
        __syncthreads();
        {   // L3: A2 -> A1 (64->64)
            bf16x8 a0 = *(const bf16x8*)&A2[(pt0 + m)*72 + quad*8];
            bf16x8 a1 = *(const bf16x8*)&A2[(pt0 + m)*72 + 32 + quad*8];
            f32x4 d = {0.f, 0.f, 0.f, 0.f};
            d = MFMA16(a0, bw3[0], d);
            d = MFMA16(a1, bw3[1], d);
#pragma unroll
            for (int r = 0; r < 4; ++r)
                A1[(pt0 + quad*4 + r)*72 + ocA] = f2bf(fmaxf(d[r] + bias3, 0.0f));
        }
        __syncthreads();
        {   // L4: A1 -> A3 (64->128), 2 oc-tiles per wave
            bf16x8 a0 = *(const bf16x8*)&A1[(pt0 + m)*72 + quad*8];
            bf16x8 a1 = *(const bf16x8*)&A1[(pt0 + m)*72 + 32 + quad*8];
#pragma unroll
            for (int r2 = 0; r2 < 2; ++r2) {
                f32x4 d = {0.f, 0.f, 0.f, 0.f};
                d = MFMA16(a0, bw4[r2][0], d);
                d = MFMA16(a1, bw4[r2][1], d);
                float bs = r2 ? bias4_1 : bias4_0;
#pragma unroll
                for (int r = 0; r < 4; ++r)
                    A3[(pt0 + quad*4 + r)*136 + oc4i[r2]] = f2bf(fmaxf(d[r] + bs, 0.0f));
            }
        }
        __syncthreads();
        {   // L5 (128 -> this block's 256-oc slice) + max-pool
            float vm = 0.0f;                        // relu outputs >= 0
#pragma unroll
            for (int pt4 = 0; pt4 < 4; ++pt4) {
                const int q0 = pt4 * 16;
                f32x4 d = {0.f, 0.f, 0.f, 0.f};
#pragma unroll
                for (int ks = 0; ks < 4; ++ks) {
                    bf16x8 a = *(const bf16x8*)&A3[(q0 + m)*136 + ks*32 + quad*8];
                    d = MFMA16(a, bw5[ks], d);
                }
#pragma unroll
                for (int r = 0; r < 4; ++r)
                    vm = fmaxf(vm, fmaxf(d[r] + bias5, 0.0f));
            }
            vm = fmaxf(vm, __shfl_xor(vm, 16, 64));
            vm = fmaxf(vm, __shfl_xor(vm, 32, 64));
            if (lane < 16)
                atomicMax((int*)&pool[b*NCC + z*256 + w*16 + lane], __float_as_int(vm));
        }
    }
}

// ---------------------------------------------------------------------------
// Head, split by OUTPUT ROWS so weight traffic scales with block count
// (R8 lesson: fused head = 4 CUs streaming 2.5 MB each = 47 us).
// head1: FC1 1024->512, grid (16,BN), 32 rows/block (2 rows/wave).
// ---------------------------------------------------------------------------
__global__ __launch_bounds__(1024) void head1_kernel(const float* __restrict__ pool,
    const float* __restrict__ fw1, const float* __restrict__ fb1,
    float* __restrict__ h1g)
{
    const int bo = blockIdx.x, b = blockIdx.y, t = threadIdx.x;
    const int lane = t & 63, w = t >> 6;
    __shared__ float g[1024];
    g[t] = pool[b*NCC + t];
    __syncthreads();
#pragma unroll
    for (int i = 0; i < 2; ++i) {
        int o = bo * 32 + w * 2 + i;
        float acc = 0.0f;
#pragma unroll
        for (int j = 0; j < 16; ++j) {
            int k = lane + (j << 6);
            acc += g[k] * fw1[o*1024 + k];
        }
#pragma unroll
        for (int m = 1; m < 64; m <<= 1) acc += __shfl_xor(acc, m, 64);
        if (lane == 0) h1g[b*512 + o] = fmaxf(acc + fb1[o], 0.0f);
    }
}

// head2: FC2 512->256, grid (8,BN), 32 rows/block (2 rows/wave).
__global__ __launch_bounds__(1024) void head2_kernel(const float* __restrict__ h1g,
    const float* __restrict__ fw2, const float* __restrict__ fb2,
    float* __restrict__ h2g)
{
    const int bo = blockIdx.x, b = blockIdx.y, t = threadIdx.x;
    const int lane = t & 63, w = t >> 6;
    __shared__ float h1[512];
    if (t < 512) h1[t] = h1g[b*512 + t];
    __syncthreads();
#pragma unroll
    for (int i = 0; i < 2; ++i) {
        int o = bo * 32 + w * 2 + i;
        float acc = 0.0f;
#pragma unroll
        for (int j = 0; j < 8; ++j) {
            int k = lane + (j << 6);
            acc += h1[k] * fw2[o*512 + k];
        }
#pragma unroll
        for (int m = 1; m < 64; m <<= 1) acc += __shfl_xor(acc, m, 64);
        if (lane == 0) h2g[b*256 + o] = fmaxf(acc + fb2[o], 0.0f);
    }
}

// head3: FC3 256->3. One block per batch (tiny).
__global__ __launch_bounds__(256) void head3_kernel(const float* __restrict__ h2g,
    const float* __restrict__ fw3, const float* __restrict__ fb3,
    float* __restrict__ out)
{
    const int b = blockIdx.x, t = threadIdx.x;
    const int lane = t & 63, w = t >> 6;
    __shared__ float h2[256];
    h2[t] = h2g[b*256 + t];
    __syncthreads();
    if (w < 3) {
        float acc = 0.0f;
#pragma unroll
        for (int j = 0; j < 4; ++j) {
            int k = lane + (j << 6);
            acc += h2[k] * fw3[w*256 + k];
        }
#pragma unroll
        for (int m = 1; m < 64; m <<= 1) acc += __shfl_xor(acc, m, 64);
        if (lane == 0) out[b*3 + w] = acc + fb3[w];
    }
}

extern "C" void kernel_launch(void* const* d_in, const int* in_sizes, int n_in,
                              void* d_out, int out_size, void* d_ws, size_t ws_size,
                              hipStream_t stream)
{
    const float* x    = (const float*)d_in[0];
    const int*   far0 = (const int*)  d_in[1];
    const float *w1 = (const float*)d_in[2],  *b1 = (const float*)d_in[3];
    const float *w2 = (const float*)d_in[4],  *b2 = (const float*)d_in[5];
    const float *w3 = (const float*)d_in[6],  *b3 = (const float*)d_in[7];
    const float *w4 = (const float*)d_in[8],  *b4 = (const float*)d_in[9];
    const float *w5 = (const float*)d_in[10], *b5 = (const float*)d_in[11];
    const float *fw1 = (const float*)d_in[12], *fb1 = (const float*)d_in[13];
    const float *fw2 = (const float*)d_in[14], *fb2 = (const float*)d_in[15];
    const float *fw3 = (const float*)d_in[16], *fb3 = (const float*)d_in[17];

    char* ws = (char*)d_ws;
    int*      ccount = (int*)     (ws + OFF_CCOUNT);
    int*      scount = (int*)     (ws + OFF_SCOUNT);
    unsigned* sbits  = (unsigned*)(ws + OFF_SBITS);
    float*    pool   = (float*)   (ws + OFF_POOL);
    int*      clist  = (int*)     (ws + OFF_CLIST);
    float*    h1g    = (float*)   (ws + OFF_H1);
    float*    h2g    = (float*)   (ws + OFF_H2);
    int*      slist  = (int*)     (ws + OFF_SLIST);

    // workspace zeroing is folded into fps_kernel
    fps_kernel<<<BN, 1024, 0, stream>>>(x, far0, clist, ccount, scount, sbits, pool);
    knn_kernel<<<dim3(NCC/CCH, BN), 1024, 0, stream>>>(x, clist, ccount, sbits, slist, scount);
    mlp_kernel<<<dim3(32, BN, 4), 1024, 0, stream>>>(x, slist, scount,
        w1,b1, w2,b2, w3,b3, w4,b4, w5,b5, pool);
    head1_kernel<<<dim3(16, BN), 1024, 0, stream>>>(pool, fw1, fb1, h1g);
    head2_kernel<<<dim3(8, BN), 1024, 0, stream>>>(h1g, fw2, fb2, h2g);
    head3_kernel<<<BN, 256, 0, stream>>>(h2g, fw3, fb3, (float*)d_out);
}